// Round 4
// baseline (708.551 us; speedup 1.0000x reference)
//
#include <hip/hip_runtime.h>
#include <hip/hip_bf16.h>
#include <math.h>

typedef __hip_bfloat16 bf16;
typedef unsigned long long ull;

#define L_    5
#define H_    1024
#define NH_   16
#define NKV_  8
#define HD_   128
#define I_    3072
#define MAXS_ 16
#define EPS_  1e-6f
#define KVE_  (L_ * NKV_ * MAXS_ * HD_)   // 81920 elements per cache tensor
#define GRID_ 512
#define SS_OFF  10240                     // float idx of rms-sum slots
#define BAR_OFF 10496                     // float idx of counter area

static __device__ __forceinline__ float bl(unsigned u){ return __uint_as_float(u << 16); }
static __device__ __forceinline__ float bh(unsigned u){ return __uint_as_float(u & 0xffff0000u); }

static __device__ __forceinline__ float wred(float v){
#pragma unroll
    for (int o = 32; o; o >>= 1) v += __shfl_xor(v, o, 64);
    return v;
}

static __device__ __forceinline__ float dot8(uint4 u, float4 a, float4 b){
    return bl(u.x)*a.x + bh(u.x)*a.y + bl(u.y)*a.z + bh(u.y)*a.w
         + bl(u.z)*b.x + bh(u.z)*b.y + bl(u.w)*b.z + bh(u.w)*b.w;
}

static __device__ __forceinline__ float rms_inv(float sumsq, float n){
    float a = sumsq / n + EPS_;
    float y = rsqrtf(a);
    y = y * (1.5f - 0.5f * a * y * y);
    return y;
}

// ---- device-scope (LLC-coherent) relaxed access for cross-block data ----
static __device__ __forceinline__ float gld(const float* p){
    return __hip_atomic_load((float*)p, __ATOMIC_RELAXED, __HIP_MEMORY_SCOPE_AGENT);
}
static __device__ __forceinline__ void gst(float* p, float v){
    __hip_atomic_store(p, v, __ATOMIC_RELAXED, __HIP_MEMORY_SCOPE_AGENT);
}
static __device__ __forceinline__ void gst8(ull* p, ull v){
    __hip_atomic_store(p, v, __ATOMIC_RELAXED, __HIP_MEMORY_SCOPE_AGENT);
}

// ---- monotone dataflow counters (one LLC line each) ----
static __device__ __forceinline__ void waitc(unsigned* c, unsigned tgt){
    while (__hip_atomic_load(c, __ATOMIC_RELAXED, __HIP_MEMORY_SCOPE_AGENT) < tgt)
        __builtin_amdgcn_s_sleep(1);
}
static __device__ __forceinline__ void incc(unsigned* c){
    __hip_atomic_fetch_add(c, 1u, __ATOMIC_RELAXED, __HIP_MEMORY_SCOPE_AGENT);
}

// dtype-adaptive scalar load/store
static __device__ __forceinline__ float ld1(const void* p, size_t i, bool b16){
    return b16 ? __uint_as_float((unsigned)((const ushort*)p)[i] << 16) : ((const float*)p)[i];
}
static __device__ __forceinline__ void st1(void* p, size_t i, float v, bool b16){
    if (b16) ((bf16*)p)[i] = __float2bfloat16(v);
    else     ((float*)p)[i] = v;
}

// element-type trait for A-stage K/V prefetch
template<bool B16> struct ET { typedef float T;
    static __device__ __forceinline__ float tof(T v){ return v; } };
template<> struct ET<true> { typedef ushort T;
    static __device__ __forceinline__ float tof(T v){ return __uint_as_float((unsigned)v << 16); } };

// ---- register-prefetched weight row (N elements, per-lane chunks) ----
template<bool B16, int N> struct Pf {
    static constexpr int C = B16 ? (N / 512) : (N / 256);
    uint4 v[C];
    __device__ __forceinline__ void load(const void* w, size_t off, int lane){
        const uint4* wp = B16 ? (const uint4*)((const ushort*)w + off)
                              : (const uint4*)((const float*)w + off);
#pragma unroll
        for (int c = 0; c < C; c++) v[c] = wp[c * 64 + lane];
    }
    __device__ __forceinline__ float dot(const float* hs, int lane) const {
        float acc = 0.f;
        if (B16) {
#pragma unroll
            for (int c = 0; c < C; c++) {
                const float4* h4 = (const float4*)&hs[c * 512 + lane * 8];
                acc += dot8(v[c], h4[0], h4[1]);
            }
        } else {
#pragma unroll
            for (int c = 0; c < C; c++) {
                float4 f = *(const float4*)&v[c];
                const float4* h = (const float4*)&hs[c * 256 + lane * 4];
                acc += f.x*h->x + f.y*h->y + f.z*h->z + f.w*h->w;
            }
        }
        return acc;
    }
};

static __device__ __forceinline__ void q_addr(int r, int l,
        const void* wq, const void* wk, const void* wv,
        float* qraw, float* kraw, float* vraw,
        const void*& w, size_t& off, float*& dst){
    if (r < NH_ * HD_) {
        w = wq; off = (size_t)l * NH_ * HD_ * H_ + (size_t)r * H_; dst = qraw + r;
    } else if (r < NH_ * HD_ + NKV_ * HD_) {
        int rk = r - NH_ * HD_;
        w = wk; off = (size_t)l * NKV_ * HD_ * H_ + (size_t)rk * H_; dst = kraw + rk;
    } else {
        int rv = r - NH_ * HD_ - NKV_ * HD_;
        w = wv; off = (size_t)l * NKV_ * HD_ * H_ + (size_t)rv * H_; dst = vraw + rv;
    }
}

// prologue: zero rms slots + counters (workspace persists across graph replays)
__global__ void k_zero(float* __restrict__ ws){
    int t = threadIdx.x;
    if (t < 16) ws[SS_OFF + t] = 0.f;
    unsigned* bar = (unsigned*)(ws + BAR_OFF);
    for (int i = t; i < 192; i += 256) bar[i] = 0u;
}

template<bool B16>
static __device__ __forceinline__ void run(
        const void* hid, int pos,
        const void* pk, const void* pv,
        const void* w_iln, const void* w_paln,
        const void* wq, const void* wk, const void* wv, const void* wo,
        const void* w_qn, const void* w_kn,
        const void* w_gate, const void* w_up, const void* w_down,
        const void* w_onorm,
        float* ws, void* out,
        float* sh, float* red, float* s_inv_p)
{
    typedef typename ET<B16>::T KVT;
    const int gid = blockIdx.x, tid = threadIdx.x;
    const int lane = tid & 63, wid = tid >> 6;

    float* x    = ws;             // 1024
    float* qraw = ws + 1024;      // 2048
    float* kraw = ws + 3072;      // 1024
    float* vraw = ws + 4096;      // 1024
    float* attn = ws + 5120;      // 2048
    float* act  = ws + 7168;      // 3072
    float* ss   = ws + SS_OFF;    // 16
    unsigned* bar  = (unsigned*)(ws + BAR_OFF);
    unsigned* icnt = bar;         // init done:   512
    unsigned* qcnt = bar + 32;    // qkv done:    512*(l+1)
    unsigned* acnt = bar + 64;    // attn done:   16*(l+1)
    unsigned* ocnt = bar + 96;    // oproj done:  256*(l+1)
    unsigned* gcnt = bar + 128;   // gateup done: 512*(l+1)
    unsigned* dcnt = bar + 160;   // down done:   256*(l+1)

    // ---- prefetch Q(0) weight rows into registers ----
    Pf<B16, H_> qA, qB;
    {
        const void* w; size_t off; float* dst;
        q_addr(gid * 8 + wid, 0, wq, wk, wv, qraw, kraw, vraw, w, off, dst);
        qA.load(w, off, lane);
        q_addr(gid * 8 + wid + 4, 0, wq, wk, wv, qraw, kraw, vraw, w, off, dst);
        qB.load(w, off, lane);
    }
    asm volatile("" ::: "memory");

    // ---- init: K/V copy (sc1 -> LLC), x = hidden, ss[0] ----
    {
        const size_t esz = B16 ? 2 : 4;
        const size_t nll = (size_t)KVE_ * esz / 8;
        const ull* sk = (const ull*)pk;
        const ull* sv = (const ull*)pv;
        ull* dk = (ull*)((char*)out + (size_t)H_ * esz);
        ull* dv = dk + nll;
        for (size_t i = (size_t)gid * 256 + tid; i < nll; i += (size_t)GRID_ * 256) {
            gst8(dk + i, sk[i]);
            gst8(dv + i, sv[i]);
        }
        if (gid == 0) {
            float s0 = 0.f;
            for (int j = tid; j < H_; j += 256) {
                float v = ld1(hid, j, B16);
                gst(&x[j], v); s0 += v * v;
            }
            s0 = wred(s0);
            if (lane == 0) red[wid] = s0;
            __syncthreads();
            if (tid == 0) gst(&ss[0], red[0] + red[1] + red[2] + red[3]);
        }
        __syncthreads();
        if (tid == 0) incc(icnt);
    }

    for (int l = 0; l < L_; ++l) {
        // ================= Stage Q: rms(x)*w_iln -> QKV GEMV =================
        if (tid == 0) {
            if (l == 0) waitc(icnt, (unsigned)GRID_);
            else        waitc(dcnt, 256u * l);
            *s_inv_p = rms_inv(gld(&ss[2 * l]), (float)H_);
        }
        __syncthreads();
        {
            float inv = *s_inv_p;
            for (int j = tid; j < H_; j += 256)
                sh[j] = gld(&x[j]) * inv * ld1(w_iln, (size_t)l * H_ + j, B16);
        }
        __syncthreads();
        {
            const void* w; size_t off; float* dst;
            q_addr(gid * 8 + wid, l, wq, wk, wv, qraw, kraw, vraw, w, off, dst);
            float acc = wred(qA.dot(sh, lane));
            if (lane == 0) gst(dst, acc);
            q_addr(gid * 8 + wid + 4, l, wq, wk, wv, qraw, kraw, vraw, w, off, dst);
            acc = wred(qB.dot(sh, lane));
            if (lane == 0) gst(dst, acc);
        }
        __syncthreads();
        if (tid == 0) incc(qcnt);

        // ---- prefetch: A-stage K/V rows, O-stage wo row, G-stage rows ----
        KVT a_k0[MAXS_], a_k1[MAXS_], a_v0[MAXS_], a_v1[MAXS_];
        size_t kco = 0, vco = 0;
        if (gid < NH_ && wid == 0) {
            int g = gid >> 1;
            kco = H_ + (size_t)l * NKV_ * MAXS_ * HD_ + (size_t)g * MAXS_ * HD_;
            vco = kco + KVE_;
            const KVT* ob = (const KVT*)out;
#pragma unroll
            for (int t = 0; t < MAXS_; t++) {
                a_k0[t] = ob[kco + t * HD_ + lane];
                a_k1[t] = ob[kco + t * HD_ + 64 + lane];
                a_v0[t] = ob[vco + t * HD_ + lane];
                a_v1[t] = ob[vco + t * HD_ + 64 + lane];
            }
        }
        Pf<B16, NH_ * HD_> oRow;
        if (gid < 256)
            oRow.load(wo, (size_t)l * H_ * NH_ * HD_ + (size_t)(gid * 4 + wid) * NH_ * HD_, lane);
        Pf<B16, H_> gA, gU, hA, hU;
        {
            int i0 = gid * 6 + wid;
            size_t offg = (size_t)l * I_ * H_ + (size_t)i0 * H_;
            gA.load(w_gate, offg, lane);
            gU.load(w_up,   offg, lane);
            if (wid < 2) {
                size_t offh = (size_t)l * I_ * H_ + (size_t)(i0 + 4) * H_;
                hA.load(w_gate, offh, lane);
                hU.load(w_up,   offh, lane);
            }
        }
        asm volatile("" ::: "memory");

        // ================= Stage A: q/k rms + rope + attention ===============
        if (gid < NH_ && wid == 0) {
            waitc(qcnt, 512u * (l + 1));    // whole-wave poll, uniform exit
            int hh = gid;
            int g  = hh >> 1;
            float fr = (float)pos * exp2f(-(float)lane * 0.31143075889569023f);
            float c = cosf(fr), s = sinf(fr);

            float q0 = gld(&qraw[hh * HD_ + lane]), q1 = gld(&qraw[hh * HD_ + 64 + lane]);
            float qi = rms_inv(wred(q0 * q0 + q1 * q1), (float)HD_);
            q0 *= qi * ld1(w_qn, (size_t)l * HD_ + lane, B16);
            q1 *= qi * ld1(w_qn, (size_t)l * HD_ + 64 + lane, B16);
            float q0r = q0 * c - q1 * s, q1r = q1 * c + q0 * s;

            float k0 = gld(&kraw[g * HD_ + lane]), k1 = gld(&kraw[g * HD_ + 64 + lane]);
            float ki = rms_inv(wred(k0 * k0 + k1 * k1), (float)HD_);
            k0 *= ki * ld1(w_kn, (size_t)l * HD_ + lane, B16);
            k1 *= ki * ld1(w_kn, (size_t)l * HD_ + 64 + lane, B16);
            float k0r = k0 * c - k1 * s, k1r = k1 * c + k0 * s;

            float v0 = gld(&vraw[g * HD_ + lane]), v1 = gld(&vraw[g * HD_ + 64 + lane]);

            const float scale = 0.08838834764831845f;  // 1/sqrt(128)
            float scb[MAXS_];
            float m = -3.0e38f;
#pragma unroll
            for (int t = 0; t < MAXS_; t++) {
                float d = (t == pos)
                    ? (q0r * k0r + q1r * k1r)
                    : (q0r * ET<B16>::tof(a_k0[t]) + q1r * ET<B16>::tof(a_k1[t]));
                d = wred(d) * scale;
                scb[t] = d;
                if (t <= pos) m = fmaxf(m, d);
            }
            float se = 0.f;
#pragma unroll
            for (int t = 0; t < MAXS_; t++) {
                float e = (t <= pos) ? expf(scb[t] - m) : 0.0f;
                scb[t] = e; se += e;
            }
            float rinv = 1.0f / se;
            float a0 = 0.f, a1 = 0.f;
#pragma unroll
            for (int t = 0; t < MAXS_; t++) {
                float pt = scb[t] * rinv;
                if (t == pos) { a0 += pt * v0; a1 += pt * v1; }
                else {
                    a0 += pt * ET<B16>::tof(a_v0[t]);
                    a1 += pt * ET<B16>::tof(a_v1[t]);
                }
            }
            gst(&attn[hh * HD_ + lane],      a0);
            gst(&attn[hh * HD_ + 64 + lane], a1);
            if ((hh & 1) == 0) {
                st1(out, kco + pos * HD_ + lane,      k0r, B16);
                st1(out, kco + pos * HD_ + 64 + lane, k1r, B16);
                st1(out, vco + pos * HD_ + lane,      v0,  B16);
                st1(out, vco + pos * HD_ + 64 + lane, v1,  B16);
            }
            asm volatile("s_waitcnt vmcnt(0)" ::: "memory");
            if (lane == 0) incc(acnt);
        }

        // ================= Stage O: x += wo @ attn (blocks 0..255) ===========
        if (gid < 256) {
            if (tid == 0) waitc(acnt, 16u * (l + 1));
            __syncthreads();
            for (int j = tid; j < NH_ * HD_; j += 256) sh[j] = gld(&attn[j]);
            __syncthreads();
            int r = gid * 4 + wid;
            float acc = wred(oRow.dot(sh, lane));
            if (lane == 0) {
                float xn = gld(&x[r]) + acc;
                gst(&x[r], xn);
                red[wid] = xn * xn;
            }
            __syncthreads();
            if (tid == 0) {
                atomicAdd(&ss[2 * l + 1], red[0] + red[1] + red[2] + red[3]);
                asm volatile("s_waitcnt vmcnt(0)" ::: "memory");
                incc(ocnt);
            }
        }

        // ================= Stage G: act = silu(gate@hs)*(up@hs) ==============
        if (tid == 0) {
            waitc(ocnt, 256u * (l + 1));
            *s_inv_p = rms_inv(gld(&ss[2 * l + 1]), (float)H_);
        }
        __syncthreads();
        {
            float inv = *s_inv_p;
            for (int j = tid; j < H_; j += 256)
                sh[j] = gld(&x[j]) * inv * ld1(w_paln, (size_t)l * H_ + j, B16);
        }
        __syncthreads();
        {
            int i0 = gid * 6 + wid;
            float ag = wred(gA.dot(sh, lane));
            float au = wred(gU.dot(sh, lane));
            if (lane == 0) {
                float sig = 1.0f / (1.0f + expf(-ag));
                gst(&act[i0], ag * sig * au);
            }
            if (wid < 2) {
                ag = wred(hA.dot(sh, lane));
                au = wred(hU.dot(sh, lane));
                if (lane == 0) {
                    float sig = 1.0f / (1.0f + expf(-ag));
                    gst(&act[i0 + 4], ag * sig * au);
                }
            }
        }
        __syncthreads();
        if (tid == 0) incc(gcnt);

        // ---- prefetch: D-stage row, next-layer Q rows ----
        Pf<B16, I_> dRow;
        if (gid < 256)
            dRow.load(w_down, (size_t)l * H_ * I_ + (size_t)(gid * 4 + wid) * I_, lane);
        if (l + 1 < L_) {
            const void* w; size_t off; float* dst;
            q_addr(gid * 8 + wid, l + 1, wq, wk, wv, qraw, kraw, vraw, w, off, dst);
            qA.load(w, off, lane);
            q_addr(gid * 8 + wid + 4, l + 1, wq, wk, wv, qraw, kraw, vraw, w, off, dst);
            qB.load(w, off, lane);
        }
        asm volatile("" ::: "memory");

        // ================= Stage D: x += w_down @ act (blocks 0..255) ========
        if (gid < 256) {
            if (tid == 0) waitc(gcnt, 512u * (l + 1));
            __syncthreads();
            for (int j = tid; j < I_; j += 256) sh[j] = gld(&act[j]);
            __syncthreads();
            int r = gid * 4 + wid;
            float acc = wred(dRow.dot(sh, lane));
            if (lane == 0) {
                float xn = gld(&x[r]) + acc;
                gst(&x[r], xn);
                red[wid] = xn * xn;
            }
            __syncthreads();
            if (tid == 0) {
                atomicAdd(&ss[2 * l + 2], red[0] + red[1] + red[2] + red[3]);
                asm volatile("s_waitcnt vmcnt(0)" ::: "memory");
                incc(dcnt);
            }
        }
    }

    // ---- final: out[0..H) = rms(x, w_onorm) ----
    if (gid == 0) {
        if (tid == 0) {
            waitc(dcnt, 256u * L_);
            *s_inv_p = rms_inv(gld(&ss[2 * L_]), (float)H_);
        }
        __syncthreads();
        float inv = *s_inv_p;
        for (int j = tid; j < H_; j += 256)
            st1(out, j, gld(&x[j]) * inv * ld1(w_onorm, j, B16), B16);
    }
}

__global__ __launch_bounds__(256, 2) void k_model(
        const void* __restrict__ hid, const int* __restrict__ pos_p,
        const void* __restrict__ pk,  const void* __restrict__ pv,
        const void* __restrict__ w_iln, const void* __restrict__ w_paln,
        const void* __restrict__ wq,  const void* __restrict__ wk,
        const void* __restrict__ wv,  const void* __restrict__ wo,
        const void* __restrict__ w_qn, const void* __restrict__ w_kn,
        const void* __restrict__ w_gate, const void* __restrict__ w_up,
        const void* __restrict__ w_down, const void* __restrict__ w_onorm,
        float* __restrict__ ws, void* __restrict__ out)
{
    __shared__ float sh[I_];
    __shared__ float red[4];
    __shared__ float s_inv;

    const bool b16 = (((const ushort*)w_onorm)[0] == 0x3F80);
    int pos = pos_p[0];
    pos = pos < 0 ? 0 : (pos > MAXS_ - 1 ? MAXS_ - 1 : pos);

    if (b16)
        run<true>(hid, pos, pk, pv, w_iln, w_paln, wq, wk, wv, wo,
                  w_qn, w_kn, w_gate, w_up, w_down, w_onorm,
                  ws, out, sh, red, &s_inv);
    else
        run<false>(hid, pos, pk, pv, w_iln, w_paln, wq, wk, wv, wo,
                   w_qn, w_kn, w_gate, w_up, w_down, w_onorm,
                   ws, out, sh, red, &s_inv);
}

extern "C" void kernel_launch(void* const* d_in, const int* in_sizes, int n_in,
                              void* d_out, int out_size, void* d_ws, size_t ws_size,
                              hipStream_t stream) {
    const void* hid     = d_in[0];
    const int*  pos     = (const int*)d_in[1];
    const void* pk      = d_in[2];
    const void* pv      = d_in[3];
    const void* w_iln   = d_in[4];
    const void* w_paln  = d_in[5];
    const void* wq      = d_in[6];
    const void* wk      = d_in[7];
    const void* wv      = d_in[8];
    const void* wo      = d_in[9];
    const void* w_qn    = d_in[10];
    const void* w_kn    = d_in[11];
    const void* w_gate  = d_in[12];
    const void* w_up    = d_in[13];
    const void* w_down  = d_in[14];
    const void* w_onorm = d_in[15];
    float* ws = (float*)d_ws;

    k_zero<<<1, 256, 0, stream>>>(ws);
    k_model<<<GRID_, 256, 0, stream>>>(hid, pos, pk, pv, w_iln, w_paln,
                                       wq, wk, wv, wo, w_qn, w_kn,
                                       w_gate, w_up, w_down, w_onorm,
                                       ws, d_out);
}

// Round 5
// 526.214 us; speedup vs baseline: 1.3465x; 1.3465x over previous
//
#include <hip/hip_runtime.h>
#include <hip/hip_bf16.h>
#include <math.h>

typedef __hip_bfloat16 bf16;
typedef unsigned long long ull;

#define L_    5
#define H_    1024
#define NH_   16
#define NKV_  8
#define HD_   128
#define I_    3072
#define MAXS_ 16
#define EPS_  1e-6f
#define KVE_  (L_ * NKV_ * MAXS_ * HD_)   // 81920 elements per cache tensor
#define GRID_ 512
#define SS_OFF  10240                     // float idx of rms-sum slots
#define BAR_OFF 10496                     // float idx of counter area
#define PF_BYTES 49152                    // 12288 elems max-stage (G/D fp32)

typedef __attribute__((address_space(1))) void as1_void;
typedef __attribute__((address_space(3))) void as3_void;

static __device__ __forceinline__ float bl(unsigned u){ return __uint_as_float(u << 16); }
static __device__ __forceinline__ float bh(unsigned u){ return __uint_as_float(u & 0xffff0000u); }

static __device__ __forceinline__ float wred(float v){
#pragma unroll
    for (int o = 32; o; o >>= 1) v += __shfl_xor(v, o, 64);
    return v;
}

static __device__ __forceinline__ float dot8(uint4 u, float4 a, float4 b){
    return bl(u.x)*a.x + bh(u.x)*a.y + bl(u.y)*a.z + bh(u.y)*a.w
         + bl(u.z)*b.x + bh(u.z)*b.y + bl(u.w)*b.z + bh(u.w)*b.w;
}

static __device__ __forceinline__ float rms_inv(float sumsq, float n){
    float a = sumsq / n + EPS_;
    float y = rsqrtf(a);
    y = y * (1.5f - 0.5f * a * y * y);
    return y;
}

// ---- device-scope (LLC-coherent) relaxed access for cross-block data ----
static __device__ __forceinline__ float gld(const float* p){
    return __hip_atomic_load((float*)p, __ATOMIC_RELAXED, __HIP_MEMORY_SCOPE_AGENT);
}
static __device__ __forceinline__ void gst(float* p, float v){
    __hip_atomic_store(p, v, __ATOMIC_RELAXED, __HIP_MEMORY_SCOPE_AGENT);
}
static __device__ __forceinline__ void gst8(ull* p, ull v){
    __hip_atomic_store(p, v, __ATOMIC_RELAXED, __HIP_MEMORY_SCOPE_AGENT);
}

// ---- monotone dataflow counters (one LLC line each) ----
static __device__ __forceinline__ void waitc(unsigned* c, unsigned tgt){
    while (__hip_atomic_load(c, __ATOMIC_RELAXED, __HIP_MEMORY_SCOPE_AGENT) < tgt)
        __builtin_amdgcn_s_sleep(1);
}
static __device__ __forceinline__ void incc(unsigned* c){
    __hip_atomic_fetch_add(c, 1u, __ATOMIC_RELAXED, __HIP_MEMORY_SCOPE_AGENT);
}

// dtype-adaptive scalar load/store
static __device__ __forceinline__ float ld1(const void* p, size_t i, bool b16){
    return b16 ? __uint_as_float((unsigned)((const ushort*)p)[i] << 16) : ((const float*)p)[i];
}
static __device__ __forceinline__ void st1(void* p, size_t i, float v, bool b16){
    if (b16) ((bf16*)p)[i] = __float2bfloat16(v);
    else     ((float*)p)[i] = v;
}

// ---- LDS weight prefetch: global -> LDS, no VGPR cost. One row of nelem
// elements; dest base wave-uniform, source per-lane (lane*16 B). ----
template<bool B16>
static __device__ __forceinline__ void pf_stage(const void* w, size_t elemoff,
                                                char* ldst, int nelem, int lane){
    const int ESZ = B16 ? 2 : 4;
    const char* g = (const char*)w + elemoff * (size_t)ESZ + (size_t)lane * 16;
    const int bytes = nelem * ESZ;
#pragma unroll
    for (int c = 0; c < bytes; c += 1024)
        __builtin_amdgcn_global_load_lds((const as1_void*)(g + c),
                                         (as3_void*)(ldst + c), 16, 0, 0);
}

// ---- dot of a prefetched LDS row against LDS vector hs ----
template<bool B16>
static __device__ __forceinline__ float pf_dot(const char* pfrow, const float* hs,
                                               int nelem, int lane){
    float acc = 0.f;
    if (B16) {
#pragma unroll
        for (int c = 0; c < nelem / 512; c++) {
            uint4 u = *(const uint4*)(pfrow + c * 1024 + lane * 16);
            const float4* h4 = (const float4*)&hs[c * 512 + lane * 8];
            acc += dot8(u, h4[0], h4[1]);
        }
    } else {
#pragma unroll
        for (int c = 0; c < nelem / 256; c++) {
            float4 f = *(const float4*)(pfrow + c * 1024 + lane * 16);
            const float4* h = (const float4*)&hs[c * 256 + lane * 4];
            acc += f.x*h->x + f.y*h->y + f.z*h->z + f.w*h->w;
        }
    }
    return acc;
}

static __device__ __forceinline__ void q_addr(int r, int l,
        const void* wq, const void* wk, const void* wv,
        float* qraw, float* kraw, float* vraw,
        const void*& w, size_t& off, float*& dst){
    if (r < NH_ * HD_) {
        w = wq; off = (size_t)l * NH_ * HD_ * H_ + (size_t)r * H_; dst = qraw + r;
    } else if (r < NH_ * HD_ + NKV_ * HD_) {
        int rk = r - NH_ * HD_;
        w = wk; off = (size_t)l * NKV_ * HD_ * H_ + (size_t)rk * H_; dst = kraw + rk;
    } else {
        int rv = r - NH_ * HD_ - NKV_ * HD_;
        w = wv; off = (size_t)l * NKV_ * HD_ * H_ + (size_t)rv * H_; dst = vraw + rv;
    }
}

// prologue: zero rms slots + counters (workspace persists across graph replays)
__global__ void k_zero(float* __restrict__ ws){
    int t = threadIdx.x;
    if (t < 16) ws[SS_OFF + t] = 0.f;
    unsigned* bar = (unsigned*)(ws + BAR_OFF);
    for (int i = t; i < 192; i += 256) bar[i] = 0u;
}

template<bool B16>
static __device__ __forceinline__ void run(
        const void* hid, int pos,
        const void* pk, const void* pv,
        const void* w_iln, const void* w_paln,
        const void* wq, const void* wk, const void* wv, const void* wo,
        const void* w_qn, const void* w_kn,
        const void* w_gate, const void* w_up, const void* w_down,
        const void* w_onorm,
        float* ws, void* out,
        float* sh, float* red, float* s_inv_p, char* pf)
{
    const int ESZ = B16 ? 2 : 4;
    const int gid = blockIdx.x, tid = threadIdx.x;
    const int lane = tid & 63, wid = tid >> 6;

    float* x    = ws;             // 1024
    float* qraw = ws + 1024;      // 2048
    float* kraw = ws + 3072;      // 1024
    float* vraw = ws + 4096;      // 1024
    float* attn = ws + 5120;      // 2048
    float* act  = ws + 7168;      // 3072
    float* ss   = ws + SS_OFF;    // 16
    unsigned* bar  = (unsigned*)(ws + BAR_OFF);
    unsigned* icnt = bar;         // init done:   512
    unsigned* qcnt = bar + 32;    // qkv done:    512*(l+1)
    unsigned* acnt = bar + 64;    // attn done:   16*(l+1)
    unsigned* ocnt = bar + 96;    // oproj done:  256*(l+1)
    unsigned* gcnt = bar + 128;   // gateup done: 512*(l+1)
    unsigned* dcnt = bar + 160;   // down done:   256*(l+1)

    // prefetch lambdas — per-wave, wave-uniform LDS dest slots
    auto PFQ = [&](int ll){
        const void* w; size_t off; float* dst;
        q_addr(gid * 8 + wid, ll, wq, wk, wv, qraw, kraw, vraw, w, off, dst);
        pf_stage<B16>(w, off, pf + (size_t)wid * 1024 * ESZ, 1024, lane);
        q_addr(gid * 8 + wid + 4, ll, wq, wk, wv, qraw, kraw, vraw, w, off, dst);
        pf_stage<B16>(w, off, pf + (size_t)(wid + 4) * 1024 * ESZ, 1024, lane);
    };
    auto PFO = [&](int ll){
        pf_stage<B16>(wo, (size_t)ll * H_ * NH_ * HD_ + (size_t)(gid * 4 + wid) * NH_ * HD_,
                      pf + (size_t)wid * 2048 * ESZ, 2048, lane);
    };
    auto PFG = [&](int ll){
        int i0 = gid * 6 + wid;
        size_t offg = (size_t)ll * I_ * H_ + (size_t)i0 * H_;
        pf_stage<B16>(w_gate, offg, pf + (size_t)(2 * wid)     * 1024 * ESZ, 1024, lane);
        pf_stage<B16>(w_up,   offg, pf + (size_t)(2 * wid + 1) * 1024 * ESZ, 1024, lane);
        if (wid < 2) {
            size_t offh = (size_t)ll * I_ * H_ + (size_t)(i0 + 4) * H_;
            pf_stage<B16>(w_gate, offh, pf + (size_t)(8 + 2 * wid) * 1024 * ESZ, 1024, lane);
            pf_stage<B16>(w_up,   offh, pf + (size_t)(9 + 2 * wid) * 1024 * ESZ, 1024, lane);
        }
    };
    auto PFD = [&](int ll){
        pf_stage<B16>(w_down, (size_t)ll * H_ * I_ + (size_t)(gid * 4 + wid) * I_,
                      pf + (size_t)wid * 3072 * ESZ, 3072, lane);
    };

    // ---- issue Q(0) prefetch, then init: K/V copy (sc1), x = hidden, ss[0] ----
    PFQ(0);
    {
        const size_t nll = (size_t)KVE_ * ESZ / 8;
        const ull* sk = (const ull*)pk;
        const ull* sv = (const ull*)pv;
        ull* dk = (ull*)((char*)out + (size_t)H_ * ESZ);
        ull* dv = dk + nll;
        for (size_t i = (size_t)gid * 256 + tid; i < nll; i += (size_t)GRID_ * 256) {
            gst8(dk + i, sk[i]);
            gst8(dv + i, sv[i]);
        }
        if (gid == 0) {
            float s0 = 0.f;
            for (int j = tid; j < H_; j += 256) {
                float v = ld1(hid, j, B16);
                gst(&x[j], v); s0 += v * v;
            }
            s0 = wred(s0);
            if (lane == 0) red[wid] = s0;
            __syncthreads();
            if (tid == 0) gst(&ss[0], red[0] + red[1] + red[2] + red[3]);
        }
        __syncthreads();
        if (tid == 0) {
            asm volatile("s_waitcnt vmcnt(0)" ::: "memory");
            incc(icnt);
        }
    }

    for (int l = 0; l < L_; ++l) {
        // ================= Stage Q: rms(x)*w_iln -> QKV GEMV =================
        if (tid == 0) {
            if (l == 0) waitc(icnt, (unsigned)GRID_);
            else        waitc(dcnt, 256u * l);
            *s_inv_p = rms_inv(gld(&ss[2 * l]), (float)H_);
        }
        __syncthreads();
        {
            float inv = *s_inv_p;
            for (int j = tid; j < H_; j += 256)
                sh[j] = gld(&x[j]) * inv * ld1(w_iln, (size_t)l * H_ + j, B16);
        }
        __syncthreads();
        asm volatile("s_waitcnt vmcnt(0)" ::: "memory");   // Q rows resident in pf
        {
            const void* w; size_t off; float* dst;
            q_addr(gid * 8 + wid, l, wq, wk, wv, qraw, kraw, vraw, w, off, dst);
            float acc = wred(pf_dot<B16>(pf + (size_t)wid * 1024 * ESZ, sh, 1024, lane));
            if (lane == 0) gst(dst, acc);
            q_addr(gid * 8 + wid + 4, l, wq, wk, wv, qraw, kraw, vraw, w, off, dst);
            acc = wred(pf_dot<B16>(pf + (size_t)(wid + 4) * 1024 * ESZ, sh, 1024, lane));
            if (lane == 0) gst(dst, acc);
        }
        __syncthreads();                                    // pf reads done, results drained
        if (tid == 0) incc(qcnt);

        // overlap: stage next weights into pf during the coming waits
        if (gid < 256) PFO(l); else PFG(l);

        // ================= Stage A: q/k rms + rope + attention (16 waves) ====
        if (gid < NH_ && wid == 0) {
            waitc(qcnt, 512u * (l + 1));
            int hh = gid, g = hh >> 1;
            float fr = (float)pos * exp2f(-(float)lane * 0.31143075889569023f);
            float c = cosf(fr), s = sinf(fr);

            float q0 = gld(&qraw[hh * HD_ + lane]), q1 = gld(&qraw[hh * HD_ + 64 + lane]);
            float qi = rms_inv(wred(q0 * q0 + q1 * q1), (float)HD_);
            q0 *= qi * ld1(w_qn, (size_t)l * HD_ + lane, B16);
            q1 *= qi * ld1(w_qn, (size_t)l * HD_ + 64 + lane, B16);
            float q0r = q0 * c - q1 * s, q1r = q1 * c + q0 * s;

            float k0 = gld(&kraw[g * HD_ + lane]), k1 = gld(&kraw[g * HD_ + 64 + lane]);
            float ki = rms_inv(wred(k0 * k0 + k1 * k1), (float)HD_);
            k0 *= ki * ld1(w_kn, (size_t)l * HD_ + lane, B16);
            k1 *= ki * ld1(w_kn, (size_t)l * HD_ + 64 + lane, B16);
            float k0r = k0 * c - k1 * s, k1r = k1 * c + k0 * s;

            float v0 = gld(&vraw[g * HD_ + lane]), v1 = gld(&vraw[g * HD_ + 64 + lane]);

            size_t kco = H_ + (size_t)l * NKV_ * MAXS_ * HD_ + (size_t)g * MAXS_ * HD_;
            size_t vco = kco + KVE_;
            const float scale = 0.08838834764831845f;  // 1/sqrt(128)

            float scb[MAXS_];
            float m = -3.0e38f;
#pragma unroll
            for (int t = 0; t < MAXS_; t++) {
                float d = (t == pos)
                    ? (q0r * k0r + q1r * k1r)
                    : (q0r * ld1(out, kco + t * HD_ + lane, B16)
                     + q1r * ld1(out, kco + t * HD_ + 64 + lane, B16));
                d = wred(d) * scale;
                scb[t] = d;
                if (t <= pos) m = fmaxf(m, d);
            }
            float se = 0.f;
#pragma unroll
            for (int t = 0; t < MAXS_; t++) {
                float e = (t <= pos) ? expf(scb[t] - m) : 0.0f;
                scb[t] = e; se += e;
            }
            float rinv = 1.0f / se;
            float a0 = 0.f, a1 = 0.f;
#pragma unroll
            for (int t = 0; t < MAXS_; t++) {
                float pt = scb[t] * rinv;
                if (t == pos) { a0 += pt * v0; a1 += pt * v1; }
                else {
                    a0 += pt * ld1(out, vco + t * HD_ + lane, B16);
                    a1 += pt * ld1(out, vco + t * HD_ + 64 + lane, B16);
                }
            }
            gst(&attn[hh * HD_ + lane],      a0);
            gst(&attn[hh * HD_ + 64 + lane], a1);
            if ((hh & 1) == 0) {
                st1(out, kco + pos * HD_ + lane,      k0r, B16);
                st1(out, kco + pos * HD_ + 64 + lane, k1r, B16);
                st1(out, vco + pos * HD_ + lane,      v0,  B16);
                st1(out, vco + pos * HD_ + 64 + lane, v1,  B16);
            }
            asm volatile("s_waitcnt vmcnt(0)" ::: "memory");
            if (lane == 0) incc(acnt);
        }

        // ================= Stage O: x += wo @ attn (blocks 0..255) ===========
        if (gid < 256) {
            if (tid == 0) waitc(acnt, 16u * (l + 1));
            __syncthreads();
            for (int j = tid; j < NH_ * HD_; j += 256) sh[j] = gld(&attn[j]);
            __syncthreads();
            asm volatile("s_waitcnt vmcnt(0)" ::: "memory");   // wo rows resident
            int r = gid * 4 + wid;
            float acc = wred(pf_dot<B16>(pf + (size_t)wid * 2048 * ESZ, sh, 2048, lane));
            if (lane == 0) {
                float xn = gld(&x[r]) + acc;
                gst(&x[r], xn);
                red[wid] = xn * xn;
            }
            __syncthreads();
            if (tid == 0) {
                atomicAdd(&ss[2 * l + 1], red[0] + red[1] + red[2] + red[3]);
                asm volatile("s_waitcnt vmcnt(0)" ::: "memory");
                incc(ocnt);
            }
            __syncthreads();          // pf reads done before re-staging
            PFG(l);
        }

        // ================= Stage G: act = silu(gate@hs)*(up@hs) ==============
        if (tid == 0) {
            waitc(ocnt, 256u * (l + 1));
            *s_inv_p = rms_inv(gld(&ss[2 * l + 1]), (float)H_);
        }
        __syncthreads();
        {
            float inv = *s_inv_p;
            for (int j = tid; j < H_; j += 256)
                sh[j] = gld(&x[j]) * inv * ld1(w_paln, (size_t)l * H_ + j, B16);
        }
        __syncthreads();
        asm volatile("s_waitcnt vmcnt(0)" ::: "memory");   // gate/up rows resident
        {
            int i0 = gid * 6 + wid;
            float ag = wred(pf_dot<B16>(pf + (size_t)(2 * wid)     * 1024 * ESZ, sh, 1024, lane));
            float au = wred(pf_dot<B16>(pf + (size_t)(2 * wid + 1) * 1024 * ESZ, sh, 1024, lane));
            if (lane == 0) {
                float sig = 1.0f / (1.0f + expf(-ag));
                gst(&act[i0], ag * sig * au);
            }
            if (wid < 2) {
                ag = wred(pf_dot<B16>(pf + (size_t)(8 + 2 * wid) * 1024 * ESZ, sh, 1024, lane));
                au = wred(pf_dot<B16>(pf + (size_t)(9 + 2 * wid) * 1024 * ESZ, sh, 1024, lane));
                if (lane == 0) {
                    float sig = 1.0f / (1.0f + expf(-ag));
                    gst(&act[i0 + 4], ag * sig * au);
                }
            }
        }
        __syncthreads();
        if (tid == 0) incc(gcnt);

        // overlap: stage next weights
        if (gid < 256) PFD(l);
        else if (l + 1 < L_) PFQ(l + 1);

        // ================= Stage D: x += w_down @ act (blocks 0..255) ========
        if (gid < 256) {
            if (tid == 0) waitc(gcnt, 512u * (l + 1));
            __syncthreads();
            for (int j = tid; j < I_; j += 256) sh[j] = gld(&act[j]);
            __syncthreads();
            asm volatile("s_waitcnt vmcnt(0)" ::: "memory");   // w_down rows resident
            int r = gid * 4 + wid;
            float acc = wred(pf_dot<B16>(pf + (size_t)wid * 3072 * ESZ, sh, 3072, lane));
            if (lane == 0) {
                float xn = gld(&x[r]) + acc;
                gst(&x[r], xn);
                red[wid] = xn * xn;
            }
            __syncthreads();
            if (tid == 0) {
                atomicAdd(&ss[2 * l + 2], red[0] + red[1] + red[2] + red[3]);
                asm volatile("s_waitcnt vmcnt(0)" ::: "memory");
                incc(dcnt);
            }
            __syncthreads();          // pf reads done before re-staging
            if (l + 1 < L_) PFQ(l + 1);
        }
    }

    // ---- final: out[0..H) = rms(x, w_onorm) ----
    if (gid == 0) {
        if (tid == 0) {
            waitc(dcnt, 256u * L_);
            *s_inv_p = rms_inv(gld(&ss[2 * L_]), (float)H_);
        }
        __syncthreads();
        float inv = *s_inv_p;
        for (int j = tid; j < H_; j += 256)
            st1(out, j, gld(&x[j]) * inv * ld1(w_onorm, j, B16), B16);
    }
}

__global__ __launch_bounds__(256, 2) void k_model(
        const void* __restrict__ hid, const int* __restrict__ pos_p,
        const void* __restrict__ pk,  const void* __restrict__ pv,
        const void* __restrict__ w_iln, const void* __restrict__ w_paln,
        const void* __restrict__ wq,  const void* __restrict__ wk,
        const void* __restrict__ wv,  const void* __restrict__ wo,
        const void* __restrict__ w_qn, const void* __restrict__ w_kn,
        const void* __restrict__ w_gate, const void* __restrict__ w_up,
        const void* __restrict__ w_down, const void* __restrict__ w_onorm,
        float* __restrict__ ws, void* __restrict__ out)
{
    __shared__ float sh[I_];
    __shared__ float red[4];
    __shared__ float s_inv;
    __shared__ __align__(16) char pf[PF_BYTES];

    const bool b16 = (((const ushort*)w_onorm)[0] == 0x3F80);
    int pos = pos_p[0];
    pos = pos < 0 ? 0 : (pos > MAXS_ - 1 ? MAXS_ - 1 : pos);

    if (b16)
        run<true>(hid, pos, pk, pv, w_iln, w_paln, wq, wk, wv, wo,
                  w_qn, w_kn, w_gate, w_up, w_down, w_onorm,
                  ws, out, sh, red, &s_inv, pf);
    else
        run<false>(hid, pos, pk, pv, w_iln, w_paln, wq, wk, wv, wo,
                   w_qn, w_kn, w_gate, w_up, w_down, w_onorm,
                   ws, out, sh, red, &s_inv, pf);
}

extern "C" void kernel_launch(void* const* d_in, const int* in_sizes, int n_in,
                              void* d_out, int out_size, void* d_ws, size_t ws_size,
                              hipStream_t stream) {
    const void* hid     = d_in[0];
    const int*  pos     = (const int*)d_in[1];
    const void* pk      = d_in[2];
    const void* pv      = d_in[3];
    const void* w_iln   = d_in[4];
    const void* w_paln  = d_in[5];
    const void* wq      = d_in[6];
    const void* wk      = d_in[7];
    const void* wv      = d_in[8];
    const void* wo      = d_in[9];
    const void* w_qn    = d_in[10];
    const void* w_kn    = d_in[11];
    const void* w_gate  = d_in[12];
    const void* w_up    = d_in[13];
    const void* w_down  = d_in[14];
    const void* w_onorm = d_in[15];
    float* ws = (float*)d_ws;

    k_zero<<<1, 256, 0, stream>>>(ws);
    k_model<<<GRID_, 256, 0, stream>>>(hid, pos, pk, pv, w_iln, w_paln,
                                       wq, wk, wv, wo, w_qn, w_kn,
                                       w_gate, w_up, w_down, w_onorm,
                                       ws, d_out);
}